// Round 5
// baseline (529.197 us; speedup 1.0000x reference)
//
#include <hip/hip_runtime.h>

// Problem constants
#define B_  4096
#define D_  1024
#define R_  2048
#define MAXD 2560

typedef _Float16 half4v __attribute__((ext_vector_type(4)));
typedef _Float16 half8v __attribute__((ext_vector_type(8)));
typedef float    f32x4  __attribute__((ext_vector_type(4)));
typedef float    f32x16 __attribute__((ext_vector_type(16)));

constexpr int BM = 128;   // M tile (batch rows)
constexpr int BN = 64;    // N tile (reservoir cols)
constexpr int BK = 32;    // K chunk

// Fragment-major LDS layout: region(blk32, ks) = 64 lanes x 16 B, stored at
// ((blk*2+ks)*512 + lane*8) halves. Wave b128 reads are sequential bursts ->
// conflict-free. Staging 8B writes land on banks (r&7)*4 + h4*2 -> uniform.

__device__ inline void split4(const f32x4 v, half4v& h, half4v& l) {
    #pragma unroll
    for (int j = 0; j < 4; ++j) {
        h[j] = (_Float16)v[j];
        l[j] = (_Float16)(v[j] - (float)h[j]);
    }
}
__device__ inline float sigmoidf_(float x) { return 1.0f / (1.0f + expf(-x)); }

// pre = X*Win^T + prev*Wres^T (K=3072), gates = X*Wgate^T (K=1024, 3 sets),
// state = o*( 0.9*f*prev + 0.1*tanh(i*pre) ), spike-subtract, fp32 store.
// fp32-faithful via 2-term fp16 split + 3 MFMAs (hh, lh, hl) per logical MAC.
__global__ __launch_bounds__(256, 2)
void reservoir_fused(const float* __restrict__ X,     // B x D
                     const float* __restrict__ P,     // B x MAXD (first R cols)
                     const float* __restrict__ Win,   // R x D
                     const float* __restrict__ Wres,  // R x R
                     const float* __restrict__ Wg,    // 3R x D
                     float* __restrict__ out)         // B x MAXD
{
    __shared__ _Float16 sAh[4096], sAl[4096];         // 128 x 32 (4 blk32 x 2 ks)
    __shared__ _Float16 sWh[4][2048], sWl[4][2048];   // 64 x 32 per set (2 nb x 2 ks)

    const int tid  = threadIdx.x;
    const int lane = tid & 63;
    const int wv   = tid >> 6;
    const int wm   = wv >> 1;          // wave M index (0..1): rows wm*64..+64
    const int wn   = wv & 1;           // wave N index (0..1): cols wn*32..+32
    const int m0   = blockIdx.y * BM;
    const int n0   = blockIdx.x * BN;

    f32x16 acc[4][2];                  // [set][mb] -> 128 VGPRs
    #pragma unroll
    for (int s = 0; s < 4; ++s)
        #pragma unroll
        for (int mb = 0; mb < 2; ++mb)
            #pragma unroll
            for (int r = 0; r < 16; ++r) acc[s][mb][r] = 0.0f;

    for (int k0 = 0; k0 < D_ + R_; k0 += BK) {
        const bool ph1 = (k0 < D_);

        // ---- stage A tile: 128 rows x 32 k (1024 slots, 4/thread) ----
        {
            const float* src; int ld, kc;
            if (ph1) { src = X; ld = D_;   kc = k0; }
            else     { src = P; ld = MAXD; kc = k0 - D_; }
            #pragma unroll
            for (int i = 0; i < 4; ++i) {
                int t = i * 256 + tid;
                int r = t >> 3, sel = t & 7, kq = sel >> 1, h4 = sel & 1;
                f32x4 v = *(const f32x4*)(src + (size_t)(m0 + r) * ld + kc + kq * 8 + h4 * 4);
                half4v h, l; split4(v, h, l);
                int off = ((r >> 5) * 2 + (kq >> 1)) * 512 + ((((kq & 1) << 5) | (r & 31)) * 8) + h4 * 4;
                *(half4v*)(&sAh[off]) = h;
                *(half4v*)(&sAl[off]) = l;
            }
        }
        // ---- stage W set 0 (Win or Wres): 64 x 32 (512 slots, 2/thread) ----
        {
            const float* src; int ld, kc;
            if (ph1) { src = Win;  ld = D_; kc = k0; }
            else     { src = Wres; ld = R_; kc = k0 - D_; }
            #pragma unroll
            for (int i = 0; i < 2; ++i) {
                int t = i * 256 + tid;
                int r = t >> 3, sel = t & 7, kq = sel >> 1, h4 = sel & 1;
                f32x4 v = *(const f32x4*)(src + (size_t)(n0 + r) * ld + kc + kq * 8 + h4 * 4);
                half4v h, l; split4(v, h, l);
                int off = ((r >> 5) * 2 + (kq >> 1)) * 512 + ((((kq & 1) << 5) | (r & 31)) * 8) + h4 * 4;
                *(half4v*)(&sWh[0][off]) = h;
                *(half4v*)(&sWl[0][off]) = l;
            }
        }
        // ---- stage gate sets (phase 1 only) ----
        if (ph1) {
            #pragma unroll
            for (int g = 0; g < 3; ++g)
                #pragma unroll
                for (int i = 0; i < 2; ++i) {
                    int t = i * 256 + tid;
                    int r = t >> 3, sel = t & 7, kq = sel >> 1, h4 = sel & 1;
                    f32x4 v = *(const f32x4*)(Wg + (size_t)(g * R_ + n0 + r) * D_ + k0 + kq * 8 + h4 * 4);
                    half4v h, l; split4(v, h, l);
                    int off = ((r >> 5) * 2 + (kq >> 1)) * 512 + ((((kq & 1) << 5) | (r & 31)) * 8) + h4 * 4;
                    *(half4v*)(&sWh[1 + g][off]) = h;
                    *(half4v*)(&sWl[1 + g][off]) = l;
                }
        }
        __syncthreads();

        // ---- MFMA: two 32x32x16 k-steps per chunk, 3-way split ----
        #pragma unroll
        for (int ks = 0; ks < 2; ++ks) {
            half8v ah0 = *(const half8v*)(&sAh[((wm * 2 + 0) * 2 + ks) * 512 + lane * 8]);
            half8v al0 = *(const half8v*)(&sAl[((wm * 2 + 0) * 2 + ks) * 512 + lane * 8]);
            half8v ah1 = *(const half8v*)(&sAh[((wm * 2 + 1) * 2 + ks) * 512 + lane * 8]);
            half8v al1 = *(const half8v*)(&sAl[((wm * 2 + 1) * 2 + ks) * 512 + lane * 8]);
            #pragma unroll
            for (int s = 0; s < 4; ++s) {
                if (!ph1 && s > 0) continue;
                half8v bh = *(const half8v*)(&sWh[s][(wn * 2 + ks) * 512 + lane * 8]);
                half8v bl = *(const half8v*)(&sWl[s][(wn * 2 + ks) * 512 + lane * 8]);
                acc[s][0] = __builtin_amdgcn_mfma_f32_32x32x16_f16(ah0, bh, acc[s][0], 0, 0, 0);
                acc[s][0] = __builtin_amdgcn_mfma_f32_32x32x16_f16(al0, bh, acc[s][0], 0, 0, 0);
                acc[s][0] = __builtin_amdgcn_mfma_f32_32x32x16_f16(ah0, bl, acc[s][0], 0, 0, 0);
                acc[s][1] = __builtin_amdgcn_mfma_f32_32x32x16_f16(ah1, bh, acc[s][1], 0, 0, 0);
                acc[s][1] = __builtin_amdgcn_mfma_f32_32x32x16_f16(al1, bh, acc[s][1], 0, 0, 0);
                acc[s][1] = __builtin_amdgcn_mfma_f32_32x32x16_f16(ah1, bl, acc[s][1], 0, 0, 0);
            }
        }
        __syncthreads();
    }

    // ---- epilogue: 32x32 C/D layout col=lane&31, row=(reg&3)+8*(reg>>2)+4*(lane>>5) ----
    const int col = n0 + wn * 32 + (lane & 31);
    const int rbase = m0 + wm * 64 + 4 * (lane >> 5);
    #pragma unroll
    for (int mb = 0; mb < 2; ++mb)
        #pragma unroll
        for (int r = 0; r < 16; ++r) {
            int row = rbase + mb * 32 + (r & 3) + 8 * (r >> 2);
            float pre = acc[0][mb][r];
            float ig  = sigmoidf_(acc[1][mb][r]);
            float fg  = sigmoidf_(acc[2][mb][r]);
            float og  = sigmoidf_(acc[3][mb][r]);
            float pv  = P[(size_t)row * MAXD + col];      // exact fp32 prev
            float st  = 0.9f * (fg * pv) + 0.1f * tanhf(ig * pre);
            st *= og;
            if (st > 0.5f) st -= 0.5f;
            out[(size_t)row * MAXD + col] = st;
        }
}

// Zero the pad region out[:, 2048:2560] (harness poisons d_out with 0xAA).
__global__ void pad_zero(float* __restrict__ out) {
    int idx = blockIdx.x * 256 + threadIdx.x;
    int row = idx >> 7;
    int c   = (idx & 127) * 4;
    *(f32x4*)(&out[(size_t)row * MAXD + R_ + c]) = (f32x4){0.f, 0.f, 0.f, 0.f};
}

extern "C" void kernel_launch(void* const* d_in, const int* in_sizes, int n_in,
                              void* d_out, int out_size, void* d_ws, size_t ws_size,
                              hipStream_t stream) {
    const float* X    = (const float*)d_in[0];
    const float* P    = (const float*)d_in[1];
    const float* Win  = (const float*)d_in[2];
    const float* Wres = (const float*)d_in[3];
    const float* Wg   = (const float*)d_in[4];
    float* out        = (float*)d_out;

    pad_zero<<<2048, 256, 0, stream>>>(out);
    dim3 grid(R_ / BN, B_ / BM);   // (32, 32) = 1024 blocks
    reservoir_fused<<<grid, 256, 0, stream>>>(X, P, Win, Wres, Wg, out);
}